// Round 1
// baseline (1448.813 us; speedup 1.0000x reference)
//
#include <hip/hip_runtime.h>

#define DD 64

// ---------------- degree kernels ----------------
__global__ void deg_kernel(const int* __restrict__ src, const int* __restrict__ dst,
                           float* __restrict__ outd, float* __restrict__ ind, int E) {
    int e = blockIdx.x * blockDim.x + threadIdx.x;
    if (e < E) {
        atomicAdd(&outd[src[e]], 1.0f);
        atomicAdd(&ind[dst[e]], 1.0f);
    }
}

__global__ void norm_kernel(float* __restrict__ outd, float* __restrict__ ind, int n) {
    int i = blockIdx.x * blockDim.x + threadIdx.x;
    if (i < n) {
        outd[i] = rsqrtf(fmaxf(outd[i], 1.0f));
        ind[i] = rsqrtf(fmaxf(ind[i], 1.0f));
    }
}

// ---------------- edge scatter: agg[dst] += h[src] * outn[src] ----------------
__global__ void scatter_kernel(const int* __restrict__ src, const int* __restrict__ dst,
                               const float* __restrict__ h, const float* __restrict__ outn,
                               float* __restrict__ agg, int E) {
    long long tid = (long long)blockIdx.x * blockDim.x + threadIdx.x;
    int e = (int)(tid >> 6);
    int d = (int)(tid & 63);
    if (e < E) {
        int s = src[e];
        int t = dst[e];
        atomicAdd(&agg[t * DD + d], h[s * DD + d] * outn[s]);
    }
}

// ---------------- fused per-node: conv matvec + residual matvec + LN + relu + JK ----------------
__global__ __launch_bounds__(256) void node_kernel(
    const float* __restrict__ agg, const float* __restrict__ inn,
    const float* __restrict__ h_in,
    const float* __restrict__ Wc, const float* __restrict__ bc,
    const float* __restrict__ Wr, const float* __restrict__ br,
    const float* __restrict__ g, const float* __restrict__ bb,
    float* __restrict__ h_out, float* __restrict__ h_final,
    int first, int n)
{
    __shared__ float sWc[DD * DD];
    __shared__ float sWr[DD * DD];
    for (int i = threadIdx.x; i < DD * DD / 4; i += blockDim.x) {
        ((float4*)sWc)[i] = ((const float4*)Wc)[i];
        ((float4*)sWr)[i] = ((const float4*)Wr)[i];
    }
    __syncthreads();

    int lane = threadIdx.x & 63;
    int wave = threadIdx.x >> 6;
    int wavesTotal = (gridDim.x * blockDim.x) >> 6;
    float bcl = bc[lane], brl = br[lane], gl = g[lane], bbl = bb[lane];

    for (int v = blockIdx.x * (blockDim.x >> 6) + wave; v < n; v += wavesTotal) {
        float xa = agg[v * DD + lane] * inn[v];
        float xh = h_in[v * DD + lane];
        float acc = bcl + brl;
        #pragma unroll
        for (int k = 0; k < DD; ++k) {
            float ak = __shfl(xa, k);
            float hk = __shfl(xh, k);
            acc = fmaf(ak, sWc[k * DD + lane], acc);
            acc = fmaf(hk, sWr[k * DD + lane], acc);
        }
        // LayerNorm across the 64 lanes (one node row per wave)
        float s = acc;
        #pragma unroll
        for (int m = 32; m >= 1; m >>= 1) s += __shfl_xor(s, m);
        float mu = s * (1.0f / 64.0f);
        float c = acc - mu;
        float vs = c * c;
        #pragma unroll
        for (int m = 32; m >= 1; m >>= 1) vs += __shfl_xor(vs, m);
        float var = vs * (1.0f / 64.0f);
        float y = c * rsqrtf(var + 1e-5f) * gl + bbl;
        y = fmaxf(y, 0.0f);                      // relu (dropout p=0)
        h_out[v * DD + lane] = y;
        h_final[v * DD + lane] = first ? y : (h_final[v * DD + lane] + y);
    }
}

// ---------------- final prediction matvec ----------------
__global__ __launch_bounds__(256) void pred_kernel(
    const float* __restrict__ h_final, const float* __restrict__ W,
    const float* __restrict__ b, float* __restrict__ out, int n)
{
    __shared__ float sW[DD * DD];
    for (int i = threadIdx.x; i < DD * DD / 4; i += blockDim.x)
        ((float4*)sW)[i] = ((const float4*)W)[i];
    __syncthreads();

    int lane = threadIdx.x & 63;
    int wave = threadIdx.x >> 6;
    int wavesTotal = (gridDim.x * blockDim.x) >> 6;
    float bl = b[lane];

    for (int v = blockIdx.x * (blockDim.x >> 6) + wave; v < n; v += wavesTotal) {
        float xh = h_final[v * DD + lane];
        float acc = bl;
        #pragma unroll
        for (int k = 0; k < DD; ++k)
            acc = fmaf(__shfl(xh, k), sW[k * DD + lane], acc);
        out[v * DD + lane] = acc;
    }
}

extern "C" void kernel_launch(void* const* d_in, const int* in_sizes, int n_in,
                              void* d_out, int out_size, void* d_ws, size_t ws_size,
                              hipStream_t stream) {
    const float* feats  = (const float*)d_in[0];
    const int*   src    = (const int*)d_in[1];
    const int*   dst    = (const int*)d_in[2];
    const float* conv_W = (const float*)d_in[3];
    const float* conv_b = (const float*)d_in[4];
    const float* res_W  = (const float*)d_in[5];
    const float* res_b  = (const float*)d_in[6];
    const float* ln_g   = (const float*)d_in[7];
    const float* ln_b   = (const float*)d_in[8];
    const float* pred_W = (const float*)d_in[9];
    const float* pred_b = (const float*)d_in[10];

    int N = in_sizes[0] / DD;
    int E = in_sizes[1];

    // workspace layout (floats): outn[N] | inn[N] | h[N*D] | agg[N*D] | h_final[N*D]
    float* outn    = (float*)d_ws;
    float* inn     = outn + N;
    float* h       = inn + N;
    float* agg     = h + (size_t)N * DD;
    float* h_final = agg + (size_t)N * DD;

    hipMemsetAsync(outn, 0, (size_t)2 * N * sizeof(float), stream);
    deg_kernel<<<(E + 255) / 256, 256, 0, stream>>>(src, dst, outn, inn, E);
    norm_kernel<<<(N + 255) / 256, 256, 0, stream>>>(outn, inn, N);

    const float* h_in = feats;
    for (int l = 0; l < 3; ++l) {
        hipMemsetAsync(agg, 0, (size_t)N * DD * sizeof(float), stream);
        long long tot = (long long)E * DD;
        scatter_kernel<<<(int)((tot + 255) / 256), 256, 0, stream>>>(src, dst, h_in, outn, agg, E);
        node_kernel<<<1024, 256, 0, stream>>>(
            agg, inn, h_in,
            conv_W + (size_t)l * DD * DD, conv_b + (size_t)l * DD,
            res_W  + (size_t)l * DD * DD, res_b  + (size_t)l * DD,
            ln_g   + (size_t)l * DD,      ln_b   + (size_t)l * DD,
            h, h_final, (l == 0) ? 1 : 0, N);
        h_in = h;
    }
    pred_kernel<<<1024, 256, 0, stream>>>(h_final, pred_W, pred_b, (float*)d_out, N);
}

// Round 3
// 1053.554 us; speedup vs baseline: 1.3752x; 1.3752x over previous
//
#include <hip/hip_runtime.h>

#define DD 64
#define SCAN_B 256

__device__ __forceinline__ float lane_bcast(float x, int k) {
    return __int_as_float(__builtin_amdgcn_readlane(__float_as_int(x), k));
}

// ---------------- degree histogram (int) ----------------
__global__ void hist_kernel(const int* __restrict__ src, const int* __restrict__ dst,
                            int* __restrict__ outd, int* __restrict__ ind, int E) {
    int e = blockIdx.x * blockDim.x + threadIdx.x;
    if (e < E) {
        atomicAdd(&outd[src[e]], 1);
        atomicAdd(&ind[dst[e]], 1);
    }
}

__global__ void norm_kernel(const int* __restrict__ outd, const int* __restrict__ ind,
                            float* __restrict__ outn, float* __restrict__ inn, int n) {
    int i = blockIdx.x * blockDim.x + threadIdx.x;
    if (i < n) {
        outn[i] = rsqrtf(fmaxf((float)outd[i], 1.0f));
        inn[i]  = rsqrtf(fmaxf((float)ind[i], 1.0f));
    }
}

// ---------------- exclusive scan of in-degrees -> rowptr ----------------
__global__ void scan1_kernel(const int* __restrict__ in, int* __restrict__ out,
                             int* __restrict__ bsums, int n) {
    __shared__ int tmp[SCAN_B];
    int gid = blockIdx.x * SCAN_B + threadIdx.x;
    int v = (gid < n) ? in[gid] : 0;
    tmp[threadIdx.x] = v;
    __syncthreads();
    for (int off = 1; off < SCAN_B; off <<= 1) {
        int t = (threadIdx.x >= off) ? tmp[threadIdx.x - off] : 0;
        __syncthreads();
        tmp[threadIdx.x] += t;
        __syncthreads();
    }
    if (gid < n) out[gid] = tmp[threadIdx.x] - v;  // exclusive within block
    if (threadIdx.x == SCAN_B - 1) bsums[blockIdx.x] = tmp[SCAN_B - 1];
}

__global__ void scan2_kernel(int* __restrict__ bsums, int nb) {
    __shared__ int tmp[512];
    int v = (threadIdx.x < nb) ? bsums[threadIdx.x] : 0;
    tmp[threadIdx.x] = v;
    __syncthreads();
    for (int off = 1; off < 512; off <<= 1) {
        int t = (threadIdx.x >= off) ? tmp[threadIdx.x - off] : 0;
        __syncthreads();
        tmp[threadIdx.x] += t;
        __syncthreads();
    }
    if (threadIdx.x < nb) bsums[threadIdx.x] = tmp[threadIdx.x] - v;  // exclusive
}

__global__ void scan3_kernel(int* __restrict__ out, const int* __restrict__ bsums,
                             int n, int E) {
    int gid = blockIdx.x * SCAN_B + threadIdx.x;
    if (gid < n) out[gid] += bsums[blockIdx.x];
    if (gid == 0) out[n] = E;
}

// ---------------- CSR fill: edges grouped by dst ----------------
__global__ void fill_kernel(const int* __restrict__ src, const int* __restrict__ dst,
                            const int* __restrict__ rowptr, int* __restrict__ cnt,
                            int* __restrict__ esrc, int E) {
    int e = blockIdx.x * blockDim.x + threadIdx.x;
    if (e < E) {
        int d = dst[e];
        int p = rowptr[d] + atomicAdd(&cnt[d], 1);
        esrc[p] = src[e];
    }
}

// ---------------- fused per-layer: CSR gather + conv/res matvec + LN + relu + JK ----------------
// NOTE: h_in and h_out MUST NOT alias (gather reads arbitrary rows of h_in
// while other waves write h_out) — caller ping-pongs buffers.
__global__ __launch_bounds__(256) void gcn_kernel(
    const int* __restrict__ rowptr, const int* __restrict__ esrc,
    const float* __restrict__ outn, const float* __restrict__ inn,
    const float* __restrict__ h_in,
    const float* __restrict__ Wc, const float* __restrict__ bc,
    const float* __restrict__ Wr, const float* __restrict__ br,
    const float* __restrict__ g, const float* __restrict__ bb,
    float* __restrict__ h_out, float* __restrict__ h_final,
    int first, int n)
{
    int lane = threadIdx.x & 63;
    int wave = threadIdx.x >> 6;
    int wavesTotal = (gridDim.x * blockDim.x) >> 6;

    // both weight matrices in VGPRs: lane j owns column j
    float wc[DD], wr[DD];
    #pragma unroll
    for (int k = 0; k < DD; ++k) {
        wc[k] = Wc[k * DD + lane];
        wr[k] = Wr[k * DD + lane];
    }
    float bias = bc[lane] + br[lane];
    float gl = g[lane], bbl = bb[lane];

    for (int v = blockIdx.x * (blockDim.x >> 6) + wave; v < n; v += wavesTotal) {
        // gather-aggregate over in-edges (CSR); lane = feature dim.
        // wave cooperatively loads up to 64 edge indices, then readlane-broadcasts
        // each so the source index is an SGPR (scalar outn load + saddr row load).
        float xa = 0.0f;
        int start = rowptr[v];
        int deg = rowptr[v + 1] - start;
        for (int base = 0; base < deg; base += 64) {
            int m = min(64, deg - base);
            int eidx = (lane < m) ? esrc[start + base + lane] : 0;
            for (int j = 0; j < m; ++j) {
                int s = __builtin_amdgcn_readlane(eidx, j);
                xa = fmaf(h_in[s * DD + lane], outn[s], xa);
            }
        }
        xa *= inn[v];
        float xh = h_in[v * DD + lane];

        // dual matvec: pure VALU (readlane broadcast + W in regs)
        float acc = bias;
        #pragma unroll
        for (int k = 0; k < DD; ++k) {
            acc = fmaf(lane_bcast(xa, k), wc[k], acc);
            acc = fmaf(lane_bcast(xh, k), wr[k], acc);
        }

        // LayerNorm across the 64 lanes
        float s = acc;
        #pragma unroll
        for (int m2 = 32; m2 >= 1; m2 >>= 1) s += __shfl_xor(s, m2);
        float mu = s * (1.0f / 64.0f);
        float c = acc - mu;
        float vs = c * c;
        #pragma unroll
        for (int m2 = 32; m2 >= 1; m2 >>= 1) vs += __shfl_xor(vs, m2);
        float var = vs * (1.0f / 64.0f);
        float y = fmaxf(c * rsqrtf(var + 1e-5f) * gl + bbl, 0.0f);

        h_out[v * DD + lane] = y;
        h_final[v * DD + lane] = first ? y : (h_final[v * DD + lane] + y);
    }
}

// ---------------- final prediction matvec ----------------
__global__ __launch_bounds__(256) void pred_kernel(
    const float* __restrict__ h_final, const float* __restrict__ W,
    const float* __restrict__ b, float* __restrict__ out, int n)
{
    int lane = threadIdx.x & 63;
    int wave = threadIdx.x >> 6;
    int wavesTotal = (gridDim.x * blockDim.x) >> 6;

    float w[DD];
    #pragma unroll
    for (int k = 0; k < DD; ++k) w[k] = W[k * DD + lane];
    float bl = b[lane];

    for (int v = blockIdx.x * (blockDim.x >> 6) + wave; v < n; v += wavesTotal) {
        float xh = h_final[v * DD + lane];
        float acc = bl;
        #pragma unroll
        for (int k = 0; k < DD; ++k)
            acc = fmaf(lane_bcast(xh, k), w[k], acc);
        out[v * DD + lane] = acc;
    }
}

extern "C" void kernel_launch(void* const* d_in, const int* in_sizes, int n_in,
                              void* d_out, int out_size, void* d_ws, size_t ws_size,
                              hipStream_t stream) {
    const float* feats  = (const float*)d_in[0];
    const int*   src    = (const int*)d_in[1];
    const int*   dst    = (const int*)d_in[2];
    const float* conv_W = (const float*)d_in[3];
    const float* conv_b = (const float*)d_in[4];
    const float* res_W  = (const float*)d_in[5];
    const float* res_b  = (const float*)d_in[6];
    const float* ln_g   = (const float*)d_in[7];
    const float* ln_b   = (const float*)d_in[8];
    const float* pred_W = (const float*)d_in[9];
    const float* pred_b = (const float*)d_in[10];

    int N = in_sizes[0] / DD;
    int E = in_sizes[1];
    int nb = (N + SCAN_B - 1) / SCAN_B;

    // workspace layout (57.6 MB, within the 77.6 MB proven-safe bound)
    int*   outd_i = (int*)d_ws;            // N
    int*   ind_i  = outd_i + N;            // N
    int*   cnt    = ind_i + N;             // N
    int*   rowptr = cnt + N;               // N+1
    int*   bsums  = rowptr + N + 1;        // 512
    int*   esrc   = bsums + 512;           // E
    float* outn   = (float*)(esrc + E);    // N
    float* inn    = outn + N;              // N
    float* hA     = inn + N;               // N*DD
    float* hfin   = hA + (size_t)N * DD;   // N*DD
    float* hB     = (float*)d_out;         // ping-pong through d_out; pred overwrites it last

    hipMemsetAsync(outd_i, 0, (size_t)3 * N * sizeof(int), stream);

    hist_kernel<<<(E + 255) / 256, 256, 0, stream>>>(src, dst, outd_i, ind_i, E);
    norm_kernel<<<(N + 255) / 256, 256, 0, stream>>>(outd_i, ind_i, outn, inn, N);

    scan1_kernel<<<nb, SCAN_B, 0, stream>>>(ind_i, rowptr, bsums, N);
    scan2_kernel<<<1, 512, 0, stream>>>(bsums, nb);
    scan3_kernel<<<nb, SCAN_B, 0, stream>>>(rowptr, bsums, N, E);
    fill_kernel<<<(E + 255) / 256, 256, 0, stream>>>(src, dst, rowptr, cnt, esrc, E);

    // ping-pong: feats -> hA -> hB(d_out) -> hA
    const float* ins[3]  = {feats, hA, hB};
    float*       outs[3] = {hA, hB, hA};
    for (int l = 0; l < 3; ++l) {
        gcn_kernel<<<1024, 256, 0, stream>>>(
            rowptr, esrc, outn, inn, ins[l],
            conv_W + (size_t)l * DD * DD, conv_b + (size_t)l * DD,
            res_W  + (size_t)l * DD * DD, res_b  + (size_t)l * DD,
            ln_g   + (size_t)l * DD,      ln_b   + (size_t)l * DD,
            outs[l], hfin, (l == 0) ? 1 : 0, N);
    }
    pred_kernel<<<1024, 256, 0, stream>>>(hfin, pred_W, pred_b, (float*)d_out, N);
}

// Round 4
// 817.990 us; speedup vs baseline: 1.7712x; 1.2880x over previous
//
#include <hip/hip_runtime.h>

#define DD 64
#define SCAN_B 256
#define WPAD 68          // padded row for transposed W in LDS (16B-aligned, bank-balanced)
#define WMAT (DD * WPAD) // 4352 floats per matrix

__device__ __forceinline__ float lane_bcast(float x, int k) {
    return __int_as_float(__builtin_amdgcn_readlane(__float_as_int(x), k));
}

// ---------------- degree histogram (int) ----------------
__global__ void hist_kernel(const int* __restrict__ src, const int* __restrict__ dst,
                            int* __restrict__ outd, int* __restrict__ ind, int E) {
    int e = blockIdx.x * blockDim.x + threadIdx.x;
    if (e < E) {
        atomicAdd(&outd[src[e]], 1);
        atomicAdd(&ind[dst[e]], 1);
    }
}

// outn = rsqrt(max(outdeg,1)); inn = rsqrt(max(indeg,1)); rs = sqrt(max(outdeg,1))
__global__ void norm_kernel(const int* __restrict__ outd, const int* __restrict__ ind,
                            float* __restrict__ outn, float* __restrict__ inn,
                            float* __restrict__ rs, int n) {
    int i = blockIdx.x * blockDim.x + threadIdx.x;
    if (i < n) {
        float od = fmaxf((float)outd[i], 1.0f);
        outn[i] = rsqrtf(od);
        rs[i]   = sqrtf(od);
        inn[i]  = rsqrtf(fmaxf((float)ind[i], 1.0f));
    }
}

// ---------------- exclusive scan of in-degrees -> rowptr ----------------
__global__ void scan1_kernel(const int* __restrict__ in, int* __restrict__ out,
                             int* __restrict__ bsums, int n) {
    __shared__ int tmp[SCAN_B];
    int gid = blockIdx.x * SCAN_B + threadIdx.x;
    int v = (gid < n) ? in[gid] : 0;
    tmp[threadIdx.x] = v;
    __syncthreads();
    for (int off = 1; off < SCAN_B; off <<= 1) {
        int t = (threadIdx.x >= off) ? tmp[threadIdx.x - off] : 0;
        __syncthreads();
        tmp[threadIdx.x] += t;
        __syncthreads();
    }
    if (gid < n) out[gid] = tmp[threadIdx.x] - v;
    if (threadIdx.x == SCAN_B - 1) bsums[blockIdx.x] = tmp[SCAN_B - 1];
}

__global__ void scan2_kernel(int* __restrict__ bsums, int nb) {
    __shared__ int tmp[512];
    int v = (threadIdx.x < nb) ? bsums[threadIdx.x] : 0;
    tmp[threadIdx.x] = v;
    __syncthreads();
    for (int off = 1; off < 512; off <<= 1) {
        int t = (threadIdx.x >= off) ? tmp[threadIdx.x - off] : 0;
        __syncthreads();
        tmp[threadIdx.x] += t;
        __syncthreads();
    }
    if (threadIdx.x < nb) bsums[threadIdx.x] = tmp[threadIdx.x] - v;
}

__global__ void scan3_kernel(int* __restrict__ out, const int* __restrict__ bsums,
                             int n, int E) {
    int gid = blockIdx.x * SCAN_B + threadIdx.x;
    if (gid < n) out[gid] += bsums[blockIdx.x];
    if (gid == 0) out[n] = E;
}

// ---------------- CSR fill: edges grouped by dst ----------------
__global__ void fill_kernel(const int* __restrict__ src, const int* __restrict__ dst,
                            const int* __restrict__ rowptr, int* __restrict__ cnt,
                            int* __restrict__ esrc, int E) {
    int e = blockIdx.x * blockDim.x + threadIdx.x;
    if (e < E) {
        int d = dst[e];
        int p = rowptr[d] + atomicAdd(&cnt[d], 1);
        esrc[p] = src[e];
    }
}

// ---------------- pre-scale: hs = feats * outn ----------------
__global__ void scale_kernel(const float* __restrict__ feats, const float* __restrict__ outn,
                             float* __restrict__ hs, int n) {
    int idx = blockIdx.x * blockDim.x + threadIdx.x;   // one float4 per thread
    if (idx < n * (DD / 4)) {
        int v = idx >> 4;
        float s = outn[v];
        float4 f = ((const float4*)feats)[idx];
        f.x *= s; f.y *= s; f.z *= s; f.w *= s;
        ((float4*)hs)[idx] = f;
    }
}

// ---------------- fused per-layer: CSR gather + dual matvec + LN + relu + JK ----------------
// hs_in is the SCALED previous-layer output (h * outn). hs_in must not alias hs_out.
__global__ __launch_bounds__(512) void gcn_kernel(
    const int* __restrict__ rowptr, const int* __restrict__ esrc,
    const float* __restrict__ inn, const float* __restrict__ rs,
    const float* __restrict__ outn,
    const float* __restrict__ hs_in,
    const float* __restrict__ Wc, const float* __restrict__ bc,
    const float* __restrict__ Wr, const float* __restrict__ br,
    const float* __restrict__ g, const float* __restrict__ bb,
    float* __restrict__ hs_out, float* __restrict__ h_final,
    int first, int n)
{
    __shared__ float sW[2 * WMAT];   // transposed: sW[j*WPAD + k] = W[k*DD + j]
    for (int idx = threadIdx.x; idx < DD * DD; idx += blockDim.x) {
        int k = idx >> 6, j = idx & 63;
        sW[j * WPAD + k]        = Wc[idx];
        sW[WMAT + j * WPAD + k] = Wr[idx];
    }
    __syncthreads();

    int lane = threadIdx.x & 63;
    int wave = threadIdx.x >> 6;
    int wavesTotal = (gridDim.x * blockDim.x) >> 6;
    const float4* wcl = (const float4*)&sW[lane * WPAD];
    const float4* wrl = (const float4*)&sW[WMAT + lane * WPAD];
    float bias = bc[lane] + br[lane];
    float gl = g[lane], bbl = bb[lane];

    for (int v = blockIdx.x * (blockDim.x >> 6) + wave; v < n; v += wavesTotal) {
        // ---- gather over in-edges: xa = sum hs_in[src] (already outn-scaled) ----
        float xa = 0.0f;
        int start = rowptr[v];
        int deg = rowptr[v + 1] - start;
        for (int base = 0; base < deg; base += 64) {
            int m = min(64, deg - base);
            int eidx = (lane < m) ? esrc[start + base + lane] : 0;
            int j = 0;
            for (; j + 3 < m; j += 4) {
                int s0 = __builtin_amdgcn_readlane(eidx, j);
                int s1 = __builtin_amdgcn_readlane(eidx, j + 1);
                int s2 = __builtin_amdgcn_readlane(eidx, j + 2);
                int s3 = __builtin_amdgcn_readlane(eidx, j + 3);
                float a0 = hs_in[(size_t)s0 * DD + lane];
                float a1 = hs_in[(size_t)s1 * DD + lane];
                float a2 = hs_in[(size_t)s2 * DD + lane];
                float a3 = hs_in[(size_t)s3 * DD + lane];
                xa += (a0 + a1) + (a2 + a3);
            }
            for (; j < m; ++j) {
                int s = __builtin_amdgcn_readlane(eidx, j);
                xa += hs_in[(size_t)s * DD + lane];
            }
        }
        xa *= inn[v];
        float xh = hs_in[(size_t)v * DD + lane] * rs[v];  // unscale self row

        // ---- dual matvec: readlane broadcast + LDS float4 weight reads ----
        float acc = bias;
        #pragma unroll
        for (int kk = 0; kk < 16; ++kk) {
            float4 wc4 = wcl[kk];
            float4 wr4 = wrl[kk];
            acc = fmaf(lane_bcast(xa, 4 * kk + 0), wc4.x, acc);
            acc = fmaf(lane_bcast(xh, 4 * kk + 0), wr4.x, acc);
            acc = fmaf(lane_bcast(xa, 4 * kk + 1), wc4.y, acc);
            acc = fmaf(lane_bcast(xh, 4 * kk + 1), wr4.y, acc);
            acc = fmaf(lane_bcast(xa, 4 * kk + 2), wc4.z, acc);
            acc = fmaf(lane_bcast(xh, 4 * kk + 2), wr4.z, acc);
            acc = fmaf(lane_bcast(xa, 4 * kk + 3), wc4.w, acc);
            acc = fmaf(lane_bcast(xh, 4 * kk + 3), wr4.w, acc);
        }

        // ---- LayerNorm across 64 lanes + relu ----
        float s = acc;
        #pragma unroll
        for (int m2 = 32; m2 >= 1; m2 >>= 1) s += __shfl_xor(s, m2);
        float mu = s * (1.0f / 64.0f);
        float c = acc - mu;
        float vs = c * c;
        #pragma unroll
        for (int m2 = 32; m2 >= 1; m2 >>= 1) vs += __shfl_xor(vs, m2);
        float var = vs * (1.0f / 64.0f);
        float y = fmaxf(c * rsqrtf(var + 1e-5f) * gl + bbl, 0.0f);

        hs_out[(size_t)v * DD + lane] = y * outn[v];   // store pre-scaled for next gather
        h_final[(size_t)v * DD + lane] = first ? y : (h_final[(size_t)v * DD + lane] + y);
    }
}

// ---------------- final prediction matvec (LDS weights) ----------------
__global__ __launch_bounds__(512) void pred_kernel(
    const float* __restrict__ h_final, const float* __restrict__ W,
    const float* __restrict__ b, float* __restrict__ out, int n)
{
    __shared__ float sW[WMAT];
    for (int idx = threadIdx.x; idx < DD * DD; idx += blockDim.x) {
        int k = idx >> 6, j = idx & 63;
        sW[j * WPAD + k] = W[idx];
    }
    __syncthreads();

    int lane = threadIdx.x & 63;
    int wave = threadIdx.x >> 6;
    int wavesTotal = (gridDim.x * blockDim.x) >> 6;
    const float4* wl = (const float4*)&sW[lane * WPAD];
    float bl = b[lane];

    for (int v = blockIdx.x * (blockDim.x >> 6) + wave; v < n; v += wavesTotal) {
        float xh = h_final[(size_t)v * DD + lane];
        float acc = bl;
        #pragma unroll
        for (int kk = 0; kk < 16; ++kk) {
            float4 w4 = wl[kk];
            acc = fmaf(lane_bcast(xh, 4 * kk + 0), w4.x, acc);
            acc = fmaf(lane_bcast(xh, 4 * kk + 1), w4.y, acc);
            acc = fmaf(lane_bcast(xh, 4 * kk + 2), w4.z, acc);
            acc = fmaf(lane_bcast(xh, 4 * kk + 3), w4.w, acc);
        }
        out[(size_t)v * DD + lane] = acc;
    }
}

extern "C" void kernel_launch(void* const* d_in, const int* in_sizes, int n_in,
                              void* d_out, int out_size, void* d_ws, size_t ws_size,
                              hipStream_t stream) {
    const float* feats  = (const float*)d_in[0];
    const int*   src    = (const int*)d_in[1];
    const int*   dst    = (const int*)d_in[2];
    const float* conv_W = (const float*)d_in[3];
    const float* conv_b = (const float*)d_in[4];
    const float* res_W  = (const float*)d_in[5];
    const float* res_b  = (const float*)d_in[6];
    const float* ln_g   = (const float*)d_in[7];
    const float* ln_b   = (const float*)d_in[8];
    const float* pred_W = (const float*)d_in[9];
    const float* pred_b = (const float*)d_in[10];

    int N = in_sizes[0] / DD;
    int E = in_sizes[1];
    int nb = (N + SCAN_B - 1) / SCAN_B;

    // workspace layout (~58.2 MB)
    int*   outd_i = (int*)d_ws;            // N
    int*   ind_i  = outd_i + N;            // N
    int*   cnt    = ind_i + N;             // N
    int*   rowptr = cnt + N;               // N+1
    int*   bsums  = rowptr + N + 1;        // 512
    int*   esrc   = bsums + 512;           // E
    float* outn   = (float*)(esrc + E);    // N
    float* inn    = outn + N;              // N
    float* rs     = inn + N;               // N
    float* hsA    = rs + N;                // N*DD  (scaled h ping)
    float* hfin   = hsA + (size_t)N * DD;  // N*DD
    float* hsB    = (float*)d_out;         // scaled h pong (pred overwrites last)

    hipMemsetAsync(outd_i, 0, (size_t)3 * N * sizeof(int), stream);

    hist_kernel<<<(E + 255) / 256, 256, 0, stream>>>(src, dst, outd_i, ind_i, E);
    norm_kernel<<<(N + 255) / 256, 256, 0, stream>>>(outd_i, ind_i, outn, inn, rs, N);

    scan1_kernel<<<nb, SCAN_B, 0, stream>>>(ind_i, rowptr, bsums, N);
    scan2_kernel<<<1, 512, 0, stream>>>(bsums, nb);
    scan3_kernel<<<nb, SCAN_B, 0, stream>>>(rowptr, bsums, N, E);
    fill_kernel<<<(E + 255) / 256, 256, 0, stream>>>(src, dst, rowptr, cnt, esrc, E);

    scale_kernel<<<(N * (DD / 4) + 255) / 256, 256, 0, stream>>>(feats, outn, hsA, N);

    // ping-pong (scaled): hsA -> hsB(d_out) -> hsA -> hsB(dead, pred overwrites)
    const float* ins[3]  = {hsA, hsB, hsA};
    float*       outs[3] = {hsB, hsA, hsB};
    for (int l = 0; l < 3; ++l) {
        gcn_kernel<<<1024, 512, 0, stream>>>(
            rowptr, esrc, inn, rs, outn, ins[l],
            conv_W + (size_t)l * DD * DD, conv_b + (size_t)l * DD,
            res_W  + (size_t)l * DD * DD, res_b  + (size_t)l * DD,
            ln_g   + (size_t)l * DD,      ln_b   + (size_t)l * DD,
            outs[l], hfin, (l == 0) ? 1 : 0, N);
    }
    pred_kernel<<<1024, 512, 0, stream>>>(hfin, pred_W, pred_b, (float*)d_out, N);
}